// Round 1
// baseline (965.655 us; speedup 1.0000x reference)
//
#include <hip/hip_runtime.h>
#include <math.h>

#define NSPH 7
#define NRAD 6
#define NC 42       // NSPH*NRAD
#define RSTRIDE 44  // padded row stride: 44 floats = 176 B, 16B-aligned rows

// Zeros of spherical Bessel j_l, l=0..6, first 6 each (fp64, ~1e-9 accurate).
__constant__ double ZD[NC] = {
  // l=0: k*pi
  3.141592653589793, 6.283185307179586, 9.424777960769380, 12.566370614359172, 15.707963267948966, 18.849555921538759,
  // l=1
  4.493409457909064, 7.725251836937707, 10.904121659428899, 14.066193912831473, 17.220755271930768, 20.371302959287563,
  // l=2
  5.763459196894550, 9.095011330476355, 12.322940970566582, 15.514603010886749, 18.689036355362822, 21.853874222709767,
  // l=3
  6.987932000500519, 10.417118547379365, 13.698023153250246, 16.923621285214318, 20.121806174454748, 23.304246988939651,
  // l=4
  8.182561452571243, 11.704907154570317, 15.039664707616530, 18.301255959541888, 21.525417733399979, 24.727565547835114,
  // l=5
  9.355812111042747, 12.966530172775334, 16.354709638669827, 19.653152101821304, 22.904550647902713, 26.127750137384344,
  // l=6
  10.512835408094290, 14.207392458842460, 17.647974902806614, 20.983463068944362, 24.262768008042153, 27.507868390660500,
};

// NORMS computed in fp64 on device: sqrt(2)/|j_{l+1}(zero)| — stable here
// (z >= pi, order <= 7 => amplification ~50x, fp64 => exact at fp32).
__global__ void norms_kernel(float* __restrict__ norms) {
  int c = threadIdx.x;
  if (c >= NC) return;
  int l = c / NRAD;
  double z = ZD[c];
  double s = sin(z), co = cos(z);
  double jm = s / z;                 // j0
  double jc = s / (z * z) - co / z;  // j1
  for (int i = 1; i <= l; ++i) {     // after loop: jc = j_{l+1}
    double jn = (2.0 * i + 1.0) / z * jc - jm;
    jm = jc; jc = jn;
  }
  norms[c] = (float)(sqrt(2.0) / fabs(jc));
}

// rbf table: one thread per (e, c) with c in [0,44); c>=42 are pad lanes.
// fp32 recurrence mirrors the reference op-for-op. Precise sincosf is
// REQUIRED: upward recurrence amplifies seed error ~7e3x at l=6, z~1.05.
__global__ __launch_bounds__(256) void rbf_kernel(const float* __restrict__ dist,
                                                  const float* __restrict__ norms,
                                                  float* __restrict__ rbf, int E) {
  int tid = blockIdx.x * 256 + threadIdx.x;
  int e = tid / RSTRIDE;
  int c = tid - e * RSTRIDE;
  if (e >= E || c >= NC) return;
  int l = c / NRAD;
  float x = dist[e] / 5.0f;          // CUTOFF=5, IEEE div to match ref
  float z = x * (float)ZD[c];
  float s, co;
  sincosf(z, &s, &co);
  float j0 = s / z;
  float res;
  if (l == 0) {
    res = j0;
  } else {
    float jm = j0;
    float jc = s / (z * z) - co / z; // j1
    for (int i = 1; i < l; ++i) {
      float jn = (float)(2 * i + 1) / z * jc - jm;
      jm = jc; jc = jn;
    }
    res = jc;
  }
  rbf[(size_t)e * RSTRIDE + c] = norms[c] * res;
}

// One thread per t. Per-wave LDS staging (64 rows x 42 floats) so global
// stores are fully coalesced float4s. LDS write stride 42 -> bank stride 10,
// 2 lanes/bank = free (m136).
__global__ __launch_bounds__(256) void gather_kernel(const float* __restrict__ angle,
                                                     const int* __restrict__ idx_kj,
                                                     const float* __restrict__ rbf,
                                                     float* __restrict__ out, int T) {
  __shared__ float lds[4 * 64 * NC]; // 43008 B -> 3 blocks/CU (LDS-limited)
  const int tid = threadIdx.x;
  const int wave = tid >> 6;
  const int lane = tid & 63;
  const long long t = (long long)blockIdx.x * 256 + tid;
  float* wlds = &lds[wave * 64 * NC];

  if (t < (long long)T) {
    float ct = cosf(angle[t]);
    // cbf[l] = sqrt((2l+1)/(4pi)) * P_l(ct), Legendre recurrence (stable)
    float cb[NSPH];
    cb[0] = 0.28209479177387814f;
    cb[1] = 0.4886025119029199f * ct;
    float pm = 1.0f, pc = ct, pn;
    pn = (3.0f * ct * pc - 1.0f * pm) / 2.0f; cb[2] = 0.6307831305050401f * pn; pm = pc; pc = pn;
    pn = (5.0f * ct * pc - 2.0f * pm) / 3.0f; cb[3] = 0.7463526651802308f * pn; pm = pc; pc = pn;
    pn = (7.0f * ct * pc - 3.0f * pm) / 4.0f; cb[4] = 0.8462843753216345f * pn; pm = pc; pc = pn;
    pn = (9.0f * ct * pc - 4.0f * pm) / 5.0f; cb[5] = 0.9356025796273889f * pn; pm = pc; pc = pn;
    pn = (11.0f * ct * pc - 5.0f * pm) / 6.0f; cb[6] = 1.0171072362820548f * pn;

    const int idx = idx_kj[t];
    const float4* row4 = (const float4*)(rbf + (size_t)idx * RSTRIDE);
    float* ml = &wlds[lane * NC];
    #pragma unroll
    for (int i = 0; i < 10; ++i) {
      float4 v = row4[i];
      const int b = i * 4;
      ml[b + 0] = v.x * cb[(b + 0) / NRAD];
      ml[b + 1] = v.y * cb[(b + 1) / NRAD];
      ml[b + 2] = v.z * cb[(b + 2) / NRAD];
      ml[b + 3] = v.w * cb[(b + 3) / NRAD];
    }
    const float2 v2 = *(const float2*)(rbf + (size_t)idx * RSTRIDE + 40);
    ml[40] = v2.x * cb[6];
    ml[41] = v2.y * cb[6];
  }
  __syncthreads();

  const long long waveT0 = (long long)blockIdx.x * 256 + wave * 64;
  if (waveT0 >= (long long)T) return;
  float* outw = out + waveT0 * NC;
  if (waveT0 + 64 <= (long long)T) {
    // full wave: 64*42 = 2688 floats = 10 float4-iters + 1 float2-iter
    const float4* l4 = (const float4*)wlds;
    float4* o4 = (float4*)outw;   // wave chunk offset = waveT0*168 B, 16B-aligned
    #pragma unroll
    for (int i = 0; i < 10; ++i) o4[i * 64 + lane] = l4[i * 64 + lane];
    ((float2*)(outw + 2560))[lane] = ((const float2*)(wlds + 2560))[lane];
  } else {
    const int total = (int)(T - waveT0) * NC;
    for (int i = lane; i < total; i += 64) outw[i] = wlds[i];
  }
}

extern "C" void kernel_launch(void* const* d_in, const int* in_sizes, int n_in,
                              void* d_out, int out_size, void* d_ws, size_t ws_size,
                              hipStream_t stream) {
  const float* dist   = (const float*)d_in[0];
  const float* angle  = (const float*)d_in[1];
  const int*   idx_kj = (const int*)d_in[2];
  float* out = (float*)d_out;
  const int E = in_sizes[0];
  const int T = in_sizes[1];

  // ws layout: [0,64) floats: norms (42 used); rbf table at +64 floats
  // (256 B, keeps 16B row alignment). Needs 256 + E*44*4 bytes (~88 MB).
  float* norms = (float*)d_ws;
  float* rbf   = (float*)d_ws + 64;

  hipLaunchKernelGGL(norms_kernel, dim3(1), dim3(64), 0, stream, norms);

  const long long tot1 = (long long)E * RSTRIDE;
  const int g1 = (int)((tot1 + 255) / 256);
  hipLaunchKernelGGL(rbf_kernel, dim3(g1), dim3(256), 0, stream, dist, norms, rbf, E);

  const int g2 = (int)(((long long)T + 255) / 256);
  hipLaunchKernelGGL(gather_kernel, dim3(g2), dim3(256), 0, stream, angle, idx_kj, rbf, out, T);
}